// Round 11
// baseline (807.526 us; speedup 1.0000x reference)
//
#include <hip/hip_runtime.h>

#define N_NODES 50000
#define N_EDGES 800000
#define C_MSG 200

typedef __bf16 bf16;
typedef __attribute__((ext_vector_type(8))) __bf16 bf16x8;
typedef __attribute__((ext_vector_type(4))) float f32x4;

static __device__ __forceinline__ unsigned int pk_bf16(float a, float b) {
    union { bf16 h[2]; unsigned int u; } cv;
    cv.h[0] = (bf16)a; cv.h[1] = (bf16)b;
    return cv.u;
}

// ===========================================================================
// Weight packers (device fns) -> MFMA B-frag order (16x16x32), biases folded.
// Fragment f at out[f*512 + lane*8 + i]; lane holds B[k][n], k=kt*32+(lane>>4)*8+i.
// Paired N-tiles: pair p covers cols p*32 + 2*(lane&15) + parity.
// ===========================================================================
static __device__ void dev_pack_wm1(int tid, const float* W, const float* bm1,
                                    bf16* out) {
    int i = tid & 7, lane = (tid >> 3) & 63, rest = tid >> 9;
    int kt = rest % 2, t = rest / 2;
    int k = kt * 32 + ((lane >> 4) * 8) + i;
    int c = lane & 15;
    int n = (t < 12) ? ((t >> 1) * 32 + 2 * c + (t & 1)) : (192 + c);
    float v = 0.f;
    if (n < C_MSG) {
        if (k < 30)       v = W[k * C_MSG + n];
        else if (k == 30) v = bm1[n];
        else if (k >= 32) v = W[(k - 2) * C_MSG + n];
    }
    out[tid] = (bf16)v;
}

static __device__ void dev_pack_wm2(int tid, const float* W, const float* bm2,
                                    bf16* out) {
    int i = tid & 7, lane = (tid >> 3) & 63, rest = tid >> 9;
    int kt = rest % 7, nt = rest / 7;
    int k = kt * 32 + ((lane >> 4) * 8) + i;
    int n = 2 * (lane & 15) + nt;
    float v = 0.f;
    if (n < 30) {
        if (k < C_MSG)       v = W[k * 30 + n];
        else if (k == C_MSG) v = bm2[n];
    }
    out[tid] = (bf16)v;
}

static __device__ void dev_pack_w2h(int tid, const float* W, const float* b2,
                                    bf16* out) {
    int i = tid & 7, lane = (tid >> 3) & 63, nt = tid >> 9;
    int k = ((lane >> 4) * 8) + i;
    int n = 2 * (lane & 15) + nt;
    float v = 0.f;
    if (n < 30) {
        if (k < 30)       v = W[k * 30 + n];
        else if (k == 30) v = b2[n];
    }
    out[tid] = (bf16)v;
}

static __device__ void dev_pack_w2o(int tid, const float* W, const float* b2,
                                    bf16* out) {
    int i = tid & 7, lane = (tid >> 3) & 63;
    int k = ((lane >> 4) * 8) + i;
    int n = lane & 15;
    float v = 0.f;
    if (n == 0) {
        if (k < 30)       v = W[k];
        else if (k == 30) v = b2[0];
    }
    out[tid] = (bf16)v;
}

static __device__ void dev_pack_sel(int tid, bf16* out) {
    int i = tid & 7, lane = (tid >> 3) & 63, f = tid >> 9;
    int kt = f >> 1, nt = f & 1;
    int kloc = ((lane >> 4) * 8) + i;
    int n = 2 * (lane & 15) + nt;
    float v = (kloc == n && n < 30) ? ((kt & 1) ? -1.f : 1.f) : 0.f;
    out[tid] = (bf16)v;
}

// ===========================================================================
// setup_a: count (3125 blocks) + pack_all (186) + node_d (196) in ONE dispatch
// ===========================================================================
__global__ __launch_bounds__(256) void setup_a(
    const int* __restrict__ dst, int* __restrict__ counts,
    const float* __restrict__ Wm1_h, const float* __restrict__ bm1_h,
    const float* __restrict__ Wm1_o, const float* __restrict__ bm1_o,
    const float* __restrict__ Wm2_h, const float* __restrict__ bm2_h,
    const float* __restrict__ Wm2_o, const float* __restrict__ bm2_o,
    const float* __restrict__ W2_h,  const float* __restrict__ b2_h,
    const float* __restrict__ W2_o,  const float* __restrict__ b2_o,
    const float* __restrict__ Wm1_d,
    bf16* __restrict__ Wm1B_h, bf16* __restrict__ Wm1B_o,
    bf16* __restrict__ Wm2B_h, bf16* __restrict__ Wm2B_o,
    bf16* __restrict__ W2B_h,  bf16* __restrict__ W2B_o,
    bf16* __restrict__ SelB,   float* __restrict__ Wm1T_d,
    const float* __restrict__ features, const float* __restrict__ W1_d,
    const float* __restrict__ b1_d, float* __restrict__ bufA) {
    int b = blockIdx.x, t = threadIdx.x;
    if (b < 3125) {                                  // count
        int e = b * 256 + t;
        if (e < N_EDGES) atomicAdd(&counts[dst[e]], 1);
    } else if (b < 3311) {                           // pack_all
        int pb = b - 3125;
        if (pb < 52)       dev_pack_wm1(pb * 256 + t, Wm1_h, bm1_h, Wm1B_h);
        else if (pb < 104) dev_pack_wm1((pb - 52) * 256 + t, Wm1_o, bm1_o, Wm1B_o);
        else if (pb < 132) dev_pack_wm2((pb - 104) * 256 + t, Wm2_h, bm2_h, Wm2B_h);
        else if (pb < 160) dev_pack_wm2((pb - 132) * 256 + t, Wm2_o, bm2_o, Wm2B_o);
        else if (pb < 164) dev_pack_w2h((pb - 160) * 256 + t, W2_h, b2_h, W2B_h);
        else if (pb < 166) dev_pack_w2o((pb - 164) * 256 + t, W2_o, b2_o, W2B_o);
        else if (pb < 182) dev_pack_sel((pb - 166) * 256 + t, SelB);
        else {
            int i = (pb - 182) * 256 + t;
            if (i < C_MSG * 4) Wm1T_d[i] = Wm1_d[(i & 3) * C_MSG + (i >> 2)];
        }
    } else {                                         // node term, layer d
        int n = (b - 3311) * 256 + t;
        if (n < N_NODES) {
            float xv = features[n];
            for (int o = 0; o < 30; ++o)
                bufA[n * 30 + o] = fmaf(xv, W1_d[o], b1_d[o]);
        }
    }
}

// Parallel scan over counts
__global__ __launch_bounds__(256) void scan_kernel(const int* __restrict__ counts,
                                                   int* __restrict__ offsets,
                                                   int* __restrict__ cursor) {
    __shared__ int ws[4];
    const int b = blockIdx.x, t = threadIdx.x;
    const int lane = t & 63, wv = t >> 6;
    int acc = 0;
    for (int i = t; i < b * 256; i += 256) acc += counts[i];
#pragma unroll
    for (int d = 32; d > 0; d >>= 1) acc += __shfl_xor(acc, d);
    if (lane == 0) ws[wv] = acc;
    __syncthreads();
    int base = ws[0] + ws[1] + ws[2] + ws[3];
    __syncthreads();
    int i = b * 256 + t;
    int v = (i < N_NODES) ? counts[i] : 0;
    int inc = v;
#pragma unroll
    for (int d = 1; d < 64; d <<= 1) {
        int u = __shfl_up(inc, d);
        if (lane >= d) inc += u;
    }
    if (lane == 63) ws[wv] = inc;
    __syncthreads();
    int waveoff = 0;
    for (int k = 0; k < wv; ++k) waveoff += ws[k];
    int excl = base + waveoff + inc - v;
    if (i < N_NODES) { offsets[i] = excl; cursor[i] = excl; }
    if (i == N_NODES - 1) offsets[N_NODES] = excl + v;
}

// scatter: ONE int4 stream {src, dst, ewbf, perm} in perm order
__global__ __launch_bounds__(256) void scatter_kernel(
    const int* __restrict__ src, const int* __restrict__ dst,
    const float* __restrict__ ew, int* __restrict__ cursor,
    int4* __restrict__ edata) {
    int e = blockIdx.x * 256 + threadIdx.x;
    if (e < N_EDGES) {
        int d = dst[e];
        int p = atomicAdd(&cursor[d], 1);
        edata[p] = make_int4(src[e], d, (int)pk_bf16(ew[2 * e], ew[2 * e + 1]), e);
    }
}

// ===========================================================================
// Layer-d edge kernel (CIN=1): full-fp32 VALU path, perm order
// ===========================================================================
__global__ __launch_bounds__(256) void edge_d_kernel(
    const float* __restrict__ x, const int4* __restrict__ edata,
    const float* __restrict__ ew,
    const float* __restrict__ Wm1T, const float* __restrict__ bm1,
    const float* __restrict__ Wm2, const float* __restrict__ bm2,
    const float* __restrict__ W2, const float* __restrict__ b2, bf16* __restrict__ msg)
{
    int t = blockIdx.x * 256 + threadIdx.x;
    int4 ed = edata[t];
    float xi = x[ed.y], xj = x[ed.x];
    int p = ed.w;
    float e0 = ew[2 * p], e1 = ew[2 * p + 1];
    float m = bm2[0];
    for (int j = 0; j < C_MSG; ++j) {
        const float* __restrict__ wr = Wm1T + j * 4;
        float h = bm1[j];
        h = fmaf(xi, wr[0], h);
        h = fmaf(xj, wr[1], h);
        h = fmaf(e0, wr[2], h);
        h = fmaf(e1, wr[3], h);
        h = fmaxf(h, 0.f);
        m = fmaf(h, Wm2[j], m);
    }
    float md = m * (xi - xj);
    for (int o = 0; o < 15; ++o) {
        float f0 = fmaf(md, W2[2 * o], b2[2 * o]);
        float f1 = fmaf(md, W2[2 * o + 1], b2[2 * o + 1]);
        *(unsigned int*)(msg + (size_t)t * 32 + 2 * o) = pk_bf16(f0, f1);
    }
}

// ===========================================================================
// MFMA edge kernel v6: h CHUNKED in LDS to double occupancy.
// v5 (R10) was latency-bound at 4 blocks/CU (LDS 34816 B cap; VGPR=64 would
// allow 8). Never materialize all 224 h-cols: chunk A = cols 0-127 (GEMM1
// pairs 0-3, one per wave) -> barrier -> GEMM2 kt=0-3 -> barrier -> chunk B =
// cols 128-223 (pairs 4,5 on w0/w1; tile12 on w2; bias/pad cols per-wave)
// -> barrier -> GEMM2 kt=4-6. h LDS 29696 -> 17408 B; total 22528 -> 7
// blocks/CU. GEMM2 accumulation order kt=0..6 preserved; every MFMA identical
// -> bit-identical output. No dynamically-indexed local arrays (R9 lesson).
// ===========================================================================
template<int COUT>
__global__ __launch_bounds__(256) void edge_mfma(
    const bf16* __restrict__ xbf, const bf16* __restrict__ xlo,
    const int4* __restrict__ edata,
    const bf16* __restrict__ Wm1B, const bf16* __restrict__ SelB,
    const bf16* __restrict__ Wm2B, const bf16* __restrict__ W2B,
    bf16* __restrict__ msg)
{
    __shared__ __align__(16) char smem_all[22528];
    bf16* hp  = (bf16*)smem_all;                  // [64][136] h-chunk
    bf16* mdp = (bf16*)(smem_all + 17408);        // [64][40]

    const int tid = threadIdx.x, w = tid >> 6, lane = tid & 63;
    const int col = lane & 15, quad = lane >> 4, row0 = quad * 4;
    const int myrow = w * 16;
    const int blk = blockIdx.x * 64;
    const int ebase = blk + myrow;

    // ---- own-tile fragments (for selector GEMM): separate descriptor ----
    int4 edown = edata[ebase + col];
    bf16x8 a0o = *(const bf16x8*)(xbf + (size_t)edown.y * 32 + quad * 8);
    bf16x8 a1o = *(const bf16x8*)(xbf + (size_t)edown.x * 32 + quad * 8);
    bf16x8 a2  = *(const bf16x8*)(xlo + (size_t)edown.y * 32 + quad * 8);
    bf16x8 a3  = *(const bf16x8*)(xlo + (size_t)edown.x * 32 + quad * 8);
    if (quad == 3) {
        union { unsigned int u; bf16 b[2]; } cv;
        cv.u = (unsigned int)edown.z;
        a1o[6] = cv.b[0];
        a1o[7] = cv.b[1];
    }

    // ---- A-frags for GEMM1, all 4 M-tiles (compile-time indices only) ----
    bf16x8 A0[4], A1[4];
#pragma unroll
    for (int t = 0; t < 4; ++t) {
        int4 ed = edata[blk + t * 16 + col];
        A0[t] = *(const bf16x8*)(xbf + (size_t)ed.y * 32 + quad * 8);
        A1[t] = *(const bf16x8*)(xbf + (size_t)ed.x * 32 + quad * 8);
        if (quad == 3) {
            union { unsigned int u; bf16 b[2]; } cv;
            cv.u = (unsigned int)ed.z;
            A1[t][6] = cv.b[0];
            A1[t][7] = cv.b[1];
        }
    }

    // ---- diff[16x32] = (hi_d - hi_s) + (lo_d - lo_s) via selector GEMM ----
    f32x4 dc0 = {0.f, 0.f, 0.f, 0.f}, dc1 = {0.f, 0.f, 0.f, 0.f};
    {
        bf16x8 b;
        b = *(const bf16x8*)(SelB + (size_t)0 * 512 + lane * 8);
        dc0 = __builtin_amdgcn_mfma_f32_16x16x32_bf16(a0o, b, dc0, 0, 0, 0);
        b = *(const bf16x8*)(SelB + (size_t)1 * 512 + lane * 8);
        dc1 = __builtin_amdgcn_mfma_f32_16x16x32_bf16(a0o, b, dc1, 0, 0, 0);
        b = *(const bf16x8*)(SelB + (size_t)2 * 512 + lane * 8);
        dc0 = __builtin_amdgcn_mfma_f32_16x16x32_bf16(a1o, b, dc0, 0, 0, 0);
        b = *(const bf16x8*)(SelB + (size_t)3 * 512 + lane * 8);
        dc1 = __builtin_amdgcn_mfma_f32_16x16x32_bf16(a1o, b, dc1, 0, 0, 0);
        b = *(const bf16x8*)(SelB + (size_t)4 * 512 + lane * 8);
        dc0 = __builtin_amdgcn_mfma_f32_16x16x32_bf16(a2, b, dc0, 0, 0, 0);
        b = *(const bf16x8*)(SelB + (size_t)5 * 512 + lane * 8);
        dc1 = __builtin_amdgcn_mfma_f32_16x16x32_bf16(a2, b, dc1, 0, 0, 0);
        b = *(const bf16x8*)(SelB + (size_t)6 * 512 + lane * 8);
        dc0 = __builtin_amdgcn_mfma_f32_16x16x32_bf16(a3, b, dc0, 0, 0, 0);
        b = *(const bf16x8*)(SelB + (size_t)7 * 512 + lane * 8);
        dc1 = __builtin_amdgcn_mfma_f32_16x16x32_bf16(a3, b, dc1, 0, 0, 0);
    }

    // ======== CHUNK A: h cols 0-127 (pair p = w per wave) ========
    {
        const bf16* Wf = Wm1B + (size_t)(4 * w) * 512 + lane * 8;
        bf16x8 be0 = *(const bf16x8*)(Wf);
        bf16x8 be1 = *(const bf16x8*)(Wf + 512);
        bf16x8 bo0 = *(const bf16x8*)(Wf + 1024);
        bf16x8 bo1 = *(const bf16x8*)(Wf + 1536);
#pragma unroll
        for (int t = 0; t < 4; ++t) {
            f32x4 ae = {0.f, 0.f, 0.f, 0.f}, ao = {0.f, 0.f, 0.f, 0.f};
            ae = __builtin_amdgcn_mfma_f32_16x16x32_bf16(A0[t], be0, ae, 0, 0, 0);
            ae = __builtin_amdgcn_mfma_f32_16x16x32_bf16(A1[t], be1, ae, 0, 0, 0);
            ao = __builtin_amdgcn_mfma_f32_16x16x32_bf16(A0[t], bo0, ao, 0, 0, 0);
            ao = __builtin_amdgcn_mfma_f32_16x16x32_bf16(A1[t], bo1, ao, 0, 0, 0);
#pragma unroll
            for (int rg = 0; rg < 4; ++rg) {
                unsigned int u = pk_bf16(fmaxf(ae[rg], 0.f), fmaxf(ao[rg], 0.f));
                *(unsigned int*)(hp + (size_t)(t * 16 + row0 + rg) * 136 +
                                 w * 32 + 2 * col) = u;
            }
        }
    }

    __syncthreads();   // chunk A complete

    // ---- GEMM2 kt=0..3 on OWN rows (local col = kt*32) ----
    f32x4 m0 = {0.f, 0.f, 0.f, 0.f}, m1 = {0.f, 0.f, 0.f, 0.f};
#pragma unroll
    for (int kt = 0; kt < 4; ++kt) {
        bf16x8 a = *(const bf16x8*)(hp + (size_t)(myrow + col) * 136 + kt * 32 + quad * 8);
        bf16x8 b0 = *(const bf16x8*)(Wm2B + (size_t)kt * 512 + lane * 8);
        bf16x8 b1 = *(const bf16x8*)(Wm2B + (size_t)(7 + kt) * 512 + lane * 8);
        m0 = __builtin_amdgcn_mfma_f32_16x16x32_bf16(a, b0, m0, 0, 0, 0);
        m1 = __builtin_amdgcn_mfma_f32_16x16x32_bf16(a, b1, m1, 0, 0, 0);
    }

    __syncthreads();   // all chunk-A reads done; safe to overwrite h

    // ======== CHUNK B: h cols 128-223 (local = global - 128) ========
    // pad/bias init on OWN rows: local col 72 (global 200) = 1.0, 73-95 = 0
    for (int i = lane; i < 16 * 24; i += 64) {
        int r = myrow + i / 24, c = 72 + i % 24;
        hp[r * 136 + c] = (c == 72) ? (bf16)1.f : (bf16)0.f;
    }
    if (w < 2) {       // pairs 4,5 -> local cols (p-4)*32 + 2*col + parity
        const bf16* Wf = Wm1B + (size_t)(4 * (4 + w)) * 512 + lane * 8;
        bf16x8 be0 = *(const bf16x8*)(Wf);
        bf16x8 be1 = *(const bf16x8*)(Wf + 512);
        bf16x8 bo0 = *(const bf16x8*)(Wf + 1024);
        bf16x8 bo1 = *(const bf16x8*)(Wf + 1536);
#pragma unroll
        for (int t = 0; t < 4; ++t) {
            f32x4 ae = {0.f, 0.f, 0.f, 0.f}, ao = {0.f, 0.f, 0.f, 0.f};
            ae = __builtin_amdgcn_mfma_f32_16x16x32_bf16(A0[t], be0, ae, 0, 0, 0);
            ae = __builtin_amdgcn_mfma_f32_16x16x32_bf16(A1[t], be1, ae, 0, 0, 0);
            ao = __builtin_amdgcn_mfma_f32_16x16x32_bf16(A0[t], bo0, ao, 0, 0, 0);
            ao = __builtin_amdgcn_mfma_f32_16x16x32_bf16(A1[t], bo1, ao, 0, 0, 0);
#pragma unroll
            for (int rg = 0; rg < 4; ++rg) {
                unsigned int u = pk_bf16(fmaxf(ae[rg], 0.f), fmaxf(ao[rg], 0.f));
                *(unsigned int*)(hp + (size_t)(t * 16 + row0 + rg) * 136 +
                                 w * 32 + 2 * col) = u;
            }
        }
    } else if (w == 2) {   // tile12: global cols 192-199 -> local 64-71
        const bf16* Wf = Wm1B + (size_t)24 * 512 + lane * 8;
        bf16x8 b0 = *(const bf16x8*)(Wf);
        bf16x8 b1 = *(const bf16x8*)(Wf + 512);
#pragma unroll
        for (int t = 0; t < 4; ++t) {
            f32x4 acc = {0.f, 0.f, 0.f, 0.f};
            acc = __builtin_amdgcn_mfma_f32_16x16x32_bf16(A0[t], b0, acc, 0, 0, 0);
            acc = __builtin_amdgcn_mfma_f32_16x16x32_bf16(A1[t], b1, acc, 0, 0, 0);
            if (col < 8) {
#pragma unroll
                for (int rg = 0; rg < 4; ++rg)
                    hp[(size_t)(t * 16 + row0 + rg) * 136 + 64 + col] =
                        (bf16)fmaxf(acc[rg], 0.f);
            }
        }
    }

    __syncthreads();   // chunk B complete

    // ---- GEMM2 kt=4..6 on OWN rows (local col = (kt-4)*32) ----
#pragma unroll
    for (int kt = 4; kt < 7; ++kt) {
        bf16x8 a = *(const bf16x8*)(hp + (size_t)(myrow + col) * 136 +
                                    (kt - 4) * 32 + quad * 8);
        bf16x8 b0 = *(const bf16x8*)(Wm2B + (size_t)kt * 512 + lane * 8);
        bf16x8 b1 = *(const bf16x8*)(Wm2B + (size_t)(7 + kt) * 512 + lane * 8);
        m0 = __builtin_amdgcn_mfma_f32_16x16x32_bf16(a, b0, m0, 0, 0, 0);
        m1 = __builtin_amdgcn_mfma_f32_16x16x32_bf16(a, b1, m1, 0, 0, 0);
    }

    // ---- md = m*diff (wave-local rows; no barrier needed) ----
#pragma unroll
    for (int rg = 0; rg < 4; ++rg) {
        unsigned int u = (col == 15) ? pk_bf16(1.f, 0.f)
                                     : pk_bf16(m0[rg] * dc0[rg], m1[rg] * dc1[rg]);
        *(unsigned int*)(mdp + (size_t)(myrow + row0 + rg) * 40 + 2 * col) = u;
    }

    // ---- GEMM3: md[16x32] @ W2[32xN] -> msg (wave-local) ----
    bf16x8 am = *(const bf16x8*)(mdp + (size_t)(myrow + col) * 40 + quad * 8);
    if (COUT == 30) {
        bf16x8 b0 = *(const bf16x8*)(W2B + lane * 8);
        bf16x8 b1 = *(const bf16x8*)(W2B + 512 + lane * 8);
        f32x4 c0 = {0.f, 0.f, 0.f, 0.f}, c1 = {0.f, 0.f, 0.f, 0.f};
        c0 = __builtin_amdgcn_mfma_f32_16x16x32_bf16(am, b0, c0, 0, 0, 0);
        c1 = __builtin_amdgcn_mfma_f32_16x16x32_bf16(am, b1, c1, 0, 0, 0);
#pragma unroll
        for (int rg = 0; rg < 4; ++rg)
            *(unsigned int*)(msg + (size_t)(ebase + row0 + rg) * 32 + 2 * col) =
                pk_bf16(c0[rg], c1[rg]);
    } else {
        bf16x8 b0 = *(const bf16x8*)(W2B + lane * 8);
        f32x4 c0 = {0.f, 0.f, 0.f, 0.f};
        c0 = __builtin_amdgcn_mfma_f32_16x16x32_bf16(am, b0, c0, 0, 0, 0);
        if (col == 0) {
#pragma unroll
            for (int rg = 0; rg < 4; ++rg)
                msg[(size_t)(ebase + row0 + rg) * 32] = (bf16)c0[rg];
        }
    }
}

// ===========================================================================
// Fused aggregation + next node term. 16 lanes per node; width-16 shuffles;
// fma order identical to the original node_kernel -> numerically identical.
// ===========================================================================
template<int CNEXT>
__global__ __launch_bounds__(256) void agg_fused(
    const bf16* __restrict__ msg, const int* __restrict__ offsets,
    const float* __restrict__ bufc,
    const float* __restrict__ W1n, const float* __restrict__ b1n,
    float* __restrict__ bufn,
    bf16* __restrict__ xbf, bf16* __restrict__ xlo) {
    int gh = (blockIdx.x * 256 + threadIdx.x) >> 4;
    int lane = threadIdx.x & 15;
    int s0 = offsets[gh], s1 = offsets[gh + 1];
    float r0 = 0.f, r1 = 0.f;
    if (lane < 15) {
        float v0 = 0.f, v1 = 0.f;
        const unsigned int* mp =
            (const unsigned int*)(msg + (size_t)s0 * 32 + lane * 2);
        int cnt = s1 - s0, j = 0;
        for (; j + 4 <= cnt; j += 4) {
            unsigned int u0 = mp[(size_t)(j + 0) * 16];
            unsigned int u1 = mp[(size_t)(j + 1) * 16];
            unsigned int u2 = mp[(size_t)(j + 2) * 16];
            unsigned int u3 = mp[(size_t)(j + 3) * 16];
            union { unsigned int u; bf16 b[2]; } c0, c1, c2, c3;
            c0.u = u0; c1.u = u1; c2.u = u2; c3.u = u3;
            v0 += (float)c0.b[0]; v1 += (float)c0.b[1];
            v0 += (float)c1.b[0]; v1 += (float)c1.b[1];
            v0 += (float)c2.b[0]; v1 += (float)c2.b[1];
            v0 += (float)c3.b[0]; v1 += (float)c3.b[1];
        }
        for (; j < cnt; ++j) {
            union { unsigned int u; bf16 b[2]; } cv;
            cv.u = mp[(size_t)j * 16];
            v0 += (float)cv.b[0]; v1 += (float)cv.b[1];
        }
        float f0 = bufc[(size_t)gh * 30 + 2 * lane] + v0;
        float f1 = bufc[(size_t)gh * 30 + 2 * lane + 1] + v1;
        r0 = fmaxf(f0, 0.f);
        r1 = fmaxf(f1, 0.f);
        bf16 h0 = (bf16)r0, h1 = (bf16)r1;
        union { bf16 h[2]; unsigned int u; } hi;
        hi.h[0] = h0; hi.h[1] = h1;
        *(unsigned int*)(xbf + (size_t)gh * 32 + 2 * lane) = hi.u;
        *(unsigned int*)(xlo + (size_t)gh * 32 + 2 * lane) =
            pk_bf16(r0 - (float)h0, r1 - (float)h1);
    } else {
        *(unsigned int*)(xbf + (size_t)gh * 32 + 30) = pk_bf16(1.f, 0.f);
        *(unsigned int*)(xlo + (size_t)gh * 32 + 30) = 0u;
    }
    // ---- next node term (fma order == original node_kernel) ----
    if (CNEXT == 30) {
        float acc0 = 0.f, acc1 = 0.f;
        if (lane < 15) { acc0 = b1n[2 * lane]; acc1 = b1n[2 * lane + 1]; }
        for (int k2 = 0; k2 < 15; ++k2) {
            float rk0 = __shfl(r0, k2, 16);
            float rk1 = __shfl(r1, k2, 16);
            if (lane < 15) {
                const float* w0 = W1n + (2 * k2) * 30 + 2 * lane;
                const float* w1 = W1n + (2 * k2 + 1) * 30 + 2 * lane;
                acc0 = fmaf(rk0, w0[0], acc0);
                acc1 = fmaf(rk0, w0[1], acc1);
                acc0 = fmaf(rk1, w1[0], acc0);
                acc1 = fmaf(rk1, w1[1], acc1);
            }
        }
        if (lane < 15) {
            bufn[(size_t)gh * 30 + 2 * lane] = acc0;
            bufn[(size_t)gh * 30 + 2 * lane + 1] = acc1;
        }
    } else {
        float acc = b1n[0];
        for (int k2 = 0; k2 < 15; ++k2) {
            float rk0 = __shfl(r0, k2, 16);
            float rk1 = __shfl(r1, k2, 16);
            acc = fmaf(rk0, W1n[2 * k2], acc);
            acc = fmaf(rk1, W1n[2 * k2 + 1], acc);
        }
        if (lane == 0) bufn[gh] = acc;
    }
}

// Final aggregation (msg COUT=1): out[gh] += msgsum
__global__ __launch_bounds__(256) void agg_last(const bf16* __restrict__ msg,
                                                const int* __restrict__ offsets,
                                                float* __restrict__ out) {
    int gh = (blockIdx.x * 256 + threadIdx.x) >> 5;
    int lane = threadIdx.x & 31;
    int s0 = offsets[gh], s1 = offsets[gh + 1];
    float v = 0.f;
    for (int j = s0 + lane; j < s1; j += 32) v += (float)msg[(size_t)j * 32];
#pragma unroll
    for (int o = 16; o > 0; o >>= 1) v += __shfl_xor(v, o);
    if (lane == 0) out[gh] += v;
}

// ===========================================================================
extern "C" void kernel_launch(void* const* d_in, const int* in_sizes, int n_in,
                              void* d_out, int out_size, void* d_ws, size_t ws_size,
                              hipStream_t stream) {
    const float* features = (const float*)d_in[0];
    const int*   edges    = (const int*)d_in[1];
    const float* ew       = (const float*)d_in[2];

    const float* W1_d  = (const float*)d_in[3];
    const float* b1_d  = (const float*)d_in[4];
    const float* Wm1_d = (const float*)d_in[5];
    const float* bm1_d = (const float*)d_in[6];
    const float* Wm2_d = (const float*)d_in[7];
    const float* bm2_d = (const float*)d_in[8];
    const float* W2_d  = (const float*)d_in[9];
    const float* b2_d  = (const float*)d_in[10];

    const float* W1_h  = (const float*)d_in[11];
    const float* b1_h  = (const float*)d_in[12];
    const float* Wm1_h = (const float*)d_in[13];
    const float* bm1_h = (const float*)d_in[14];
    const float* Wm2_h = (const float*)d_in[15];
    const float* bm2_h = (const float*)d_in[16];
    const float* W2_h  = (const float*)d_in[17];
    const float* b2_h  = (const float*)d_in[18];

    const float* W1_o  = (const float*)d_in[19];
    const float* b1_o  = (const float*)d_in[20];
    const float* Wm1_o = (const float*)d_in[21];
    const float* bm1_o = (const float*)d_in[22];
    const float* Wm2_o = (const float*)d_in[23];
    const float* bm2_o = (const float*)d_in[24];
    const float* W2_o  = (const float*)d_in[25];
    const float* b2_o  = (const float*)d_in[26];

    const int* src = edges;
    const int* dst = edges + N_EDGES;
    float* out = (float*)d_out;

    // ---- workspace carve-up ----
    char* p = (char*)d_ws;
    auto alloc = [&](size_t bytes) { char* r = p; p += (bytes + 63) & ~(size_t)63; return r; };
    float* bufA    = (float*)alloc((size_t)N_NODES * 30 * 4);
    float* bufB    = (float*)alloc((size_t)N_NODES * 30 * 4);
    bf16*  msg     = (bf16*) alloc((size_t)N_EDGES * 32 * 2);
    bf16*  xbf     = (bf16*) alloc((size_t)N_NODES * 32 * 2);
    bf16*  xlo     = (bf16*) alloc((size_t)N_NODES * 32 * 2);
    int*   counts  = (int*)  alloc((size_t)N_NODES * 4);
    int*   offsets = (int*)  alloc((size_t)(N_NODES + 1) * 4);
    int*   cursor  = (int*)  alloc((size_t)N_NODES * 4);
    int4*  edata   = (int4*) alloc((size_t)N_EDGES * 16);
    float* Wm1T_d  = (float*)alloc((size_t)C_MSG * 4 * 4);
    bf16*  Wm1B_h  = (bf16*) alloc((size_t)26 * 512 * 2);
    bf16*  Wm1B_o  = (bf16*) alloc((size_t)26 * 512 * 2);
    bf16*  Wm2B_h  = (bf16*) alloc((size_t)14 * 512 * 2);
    bf16*  Wm2B_o  = (bf16*) alloc((size_t)14 * 512 * 2);
    bf16*  W2B_h   = (bf16*) alloc((size_t)2 * 512 * 2);
    bf16*  W2B_o   = (bf16*) alloc((size_t)1 * 512 * 2);
    bf16*  SelB    = (bf16*) alloc((size_t)8 * 512 * 2);

    // ---- setup ----
    hipMemsetAsync(counts, 0, (size_t)N_NODES * 4, stream);
    setup_a<<<3507, 256, 0, stream>>>(dst, counts,
        Wm1_h, bm1_h, Wm1_o, bm1_o, Wm2_h, bm2_h, Wm2_o, bm2_o,
        W2_h, b2_h, W2_o, b2_o, Wm1_d,
        Wm1B_h, Wm1B_o, Wm2B_h, Wm2B_o, W2B_h, W2B_o, SelB, Wm1T_d,
        features, W1_d, b1_d, bufA);
    scan_kernel<<<(N_NODES + 255) / 256, 256, 0, stream>>>(counts, offsets, cursor);
    scatter_kernel<<<N_EDGES / 256, 256, 0, stream>>>(src, dst, ew, cursor, edata);

    dim3 tb(256);
    dim3 eb_mfma(N_EDGES / 64);
    dim3 eb_valu(N_EDGES / 256);
    dim3 ab16(N_NODES * 16 / 256);
    dim3 ab32(N_NODES * 32 / 256);

    // ---- layer d ----
    edge_d_kernel<<<eb_valu, tb, 0, stream>>>(features, edata, ew,
        Wm1T_d, bm1_d, Wm2_d, bm2_d, W2_d, b2_d, msg);
    agg_fused<30><<<ab16, tb, 0, stream>>>(msg, offsets, bufA, W1_h, b1_h, bufB, xbf, xlo);

    // ---- h1 ----
    edge_mfma<30><<<eb_mfma, tb, 0, stream>>>(xbf, xlo, edata,
        Wm1B_h, SelB, Wm2B_h, W2B_h, msg);
    agg_fused<30><<<ab16, tb, 0, stream>>>(msg, offsets, bufB, W1_h, b1_h, bufA, xbf, xlo);

    // ---- h2 ----
    edge_mfma<30><<<eb_mfma, tb, 0, stream>>>(xbf, xlo, edata,
        Wm1B_h, SelB, Wm2B_h, W2B_h, msg);
    agg_fused<30><<<ab16, tb, 0, stream>>>(msg, offsets, bufA, W1_h, b1_h, bufB, xbf, xlo);

    // ---- h3 (next node term = output layer -> writes d_out) ----
    edge_mfma<30><<<eb_mfma, tb, 0, stream>>>(xbf, xlo, edata,
        Wm1B_h, SelB, Wm2B_h, W2B_h, msg);
    agg_fused<1><<<ab16, tb, 0, stream>>>(msg, offsets, bufB, W1_o, b1_o, out, xbf, xlo);

    // ---- output layer ----
    edge_mfma<1><<<eb_mfma, tb, 0, stream>>>(xbf, xlo, edata,
        Wm1B_o, SelB, Wm2B_o, W2B_o, msg);
    agg_last<<<ab32, tb, 0, stream>>>(msg, offsets, out);
}

// Round 12
// 761.767 us; speedup vs baseline: 1.0601x; 1.0601x over previous
//
#include <hip/hip_runtime.h>

#define N_NODES 50000
#define N_EDGES 800000
#define C_MSG 200

typedef __bf16 bf16;
typedef __attribute__((ext_vector_type(8))) __bf16 bf16x8;
typedef __attribute__((ext_vector_type(4))) float f32x4;

static __device__ __forceinline__ unsigned int pk_bf16(float a, float b) {
    union { bf16 h[2]; unsigned int u; } cv;
    cv.h[0] = (bf16)a; cv.h[1] = (bf16)b;
    return cv.u;
}

// ===========================================================================
// Weight packers (device fns) -> MFMA B-frag order (16x16x32), biases folded.
// Fragment f at out[f*512 + lane*8 + i]; lane holds B[k][n], k=kt*32+(lane>>4)*8+i.
// Paired N-tiles: pair p covers cols p*32 + 2*(lane&15) + parity.
// ===========================================================================
static __device__ void dev_pack_wm1(int tid, const float* W, const float* bm1,
                                    bf16* out) {
    int i = tid & 7, lane = (tid >> 3) & 63, rest = tid >> 9;
    int kt = rest % 2, t = rest / 2;
    int k = kt * 32 + ((lane >> 4) * 8) + i;
    int c = lane & 15;
    int n = (t < 12) ? ((t >> 1) * 32 + 2 * c + (t & 1)) : (192 + c);
    float v = 0.f;
    if (n < C_MSG) {
        if (k < 30)       v = W[k * C_MSG + n];
        else if (k == 30) v = bm1[n];
        else if (k >= 32) v = W[(k - 2) * C_MSG + n];
    }
    out[tid] = (bf16)v;
}

static __device__ void dev_pack_wm2(int tid, const float* W, const float* bm2,
                                    bf16* out) {
    int i = tid & 7, lane = (tid >> 3) & 63, rest = tid >> 9;
    int kt = rest % 7, nt = rest / 7;
    int k = kt * 32 + ((lane >> 4) * 8) + i;
    int n = 2 * (lane & 15) + nt;
    float v = 0.f;
    if (n < 30) {
        if (k < C_MSG)       v = W[k * 30 + n];
        else if (k == C_MSG) v = bm2[n];
    }
    out[tid] = (bf16)v;
}

static __device__ void dev_pack_w2h(int tid, const float* W, const float* b2,
                                    bf16* out) {
    int i = tid & 7, lane = (tid >> 3) & 63, nt = tid >> 9;
    int k = ((lane >> 4) * 8) + i;
    int n = 2 * (lane & 15) + nt;
    float v = 0.f;
    if (n < 30) {
        if (k < 30)       v = W[k * 30 + n];
        else if (k == 30) v = b2[n];
    }
    out[tid] = (bf16)v;
}

static __device__ void dev_pack_w2o(int tid, const float* W, const float* b2,
                                    bf16* out) {
    int i = tid & 7, lane = (tid >> 3) & 63;
    int k = ((lane >> 4) * 8) + i;
    int n = lane & 15;
    float v = 0.f;
    if (n == 0) {
        if (k < 30)       v = W[k];
        else if (k == 30) v = b2[0];
    }
    out[tid] = (bf16)v;
}

static __device__ void dev_pack_sel(int tid, bf16* out) {
    int i = tid & 7, lane = (tid >> 3) & 63, f = tid >> 9;
    int kt = f >> 1, nt = f & 1;
    int kloc = ((lane >> 4) * 8) + i;
    int n = 2 * (lane & 15) + nt;
    float v = (kloc == n && n < 30) ? ((kt & 1) ? -1.f : 1.f) : 0.f;
    out[tid] = (bf16)v;
}

// ===========================================================================
// setup_a: count (3125 blocks) + pack_all (186) + node_d (196) in ONE dispatch
// ===========================================================================
__global__ __launch_bounds__(256) void setup_a(
    const int* __restrict__ dst, int* __restrict__ counts,
    const float* __restrict__ Wm1_h, const float* __restrict__ bm1_h,
    const float* __restrict__ Wm1_o, const float* __restrict__ bm1_o,
    const float* __restrict__ Wm2_h, const float* __restrict__ bm2_h,
    const float* __restrict__ Wm2_o, const float* __restrict__ bm2_o,
    const float* __restrict__ W2_h,  const float* __restrict__ b2_h,
    const float* __restrict__ W2_o,  const float* __restrict__ b2_o,
    const float* __restrict__ Wm1_d,
    bf16* __restrict__ Wm1B_h, bf16* __restrict__ Wm1B_o,
    bf16* __restrict__ Wm2B_h, bf16* __restrict__ Wm2B_o,
    bf16* __restrict__ W2B_h,  bf16* __restrict__ W2B_o,
    bf16* __restrict__ SelB,   float* __restrict__ Wm1T_d,
    const float* __restrict__ features, const float* __restrict__ W1_d,
    const float* __restrict__ b1_d, float* __restrict__ bufA) {
    int b = blockIdx.x, t = threadIdx.x;
    if (b < 3125) {                                  // count
        int e = b * 256 + t;
        if (e < N_EDGES) atomicAdd(&counts[dst[e]], 1);
    } else if (b < 3311) {                           // pack_all
        int pb = b - 3125;
        if (pb < 52)       dev_pack_wm1(pb * 256 + t, Wm1_h, bm1_h, Wm1B_h);
        else if (pb < 104) dev_pack_wm1((pb - 52) * 256 + t, Wm1_o, bm1_o, Wm1B_o);
        else if (pb < 132) dev_pack_wm2((pb - 104) * 256 + t, Wm2_h, bm2_h, Wm2B_h);
        else if (pb < 160) dev_pack_wm2((pb - 132) * 256 + t, Wm2_o, bm2_o, Wm2B_o);
        else if (pb < 164) dev_pack_w2h((pb - 160) * 256 + t, W2_h, b2_h, W2B_h);
        else if (pb < 166) dev_pack_w2o((pb - 164) * 256 + t, W2_o, b2_o, W2B_o);
        else if (pb < 182) dev_pack_sel((pb - 166) * 256 + t, SelB);
        else {
            int i = (pb - 182) * 256 + t;
            if (i < C_MSG * 4) Wm1T_d[i] = Wm1_d[(i & 3) * C_MSG + (i >> 2)];
        }
    } else {                                         // node term, layer d
        int n = (b - 3311) * 256 + t;
        if (n < N_NODES) {
            float xv = features[n];
            for (int o = 0; o < 30; ++o)
                bufA[n * 30 + o] = fmaf(xv, W1_d[o], b1_d[o]);
        }
    }
}

// Parallel scan over counts
__global__ __launch_bounds__(256) void scan_kernel(const int* __restrict__ counts,
                                                   int* __restrict__ offsets,
                                                   int* __restrict__ cursor) {
    __shared__ int ws[4];
    const int b = blockIdx.x, t = threadIdx.x;
    const int lane = t & 63, wv = t >> 6;
    int acc = 0;
    for (int i = t; i < b * 256; i += 256) acc += counts[i];
#pragma unroll
    for (int d = 32; d > 0; d >>= 1) acc += __shfl_xor(acc, d);
    if (lane == 0) ws[wv] = acc;
    __syncthreads();
    int base = ws[0] + ws[1] + ws[2] + ws[3];
    __syncthreads();
    int i = b * 256 + t;
    int v = (i < N_NODES) ? counts[i] : 0;
    int inc = v;
#pragma unroll
    for (int d = 1; d < 64; d <<= 1) {
        int u = __shfl_up(inc, d);
        if (lane >= d) inc += u;
    }
    if (lane == 63) ws[wv] = inc;
    __syncthreads();
    int waveoff = 0;
    for (int k = 0; k < wv; ++k) waveoff += ws[k];
    int excl = base + waveoff + inc - v;
    if (i < N_NODES) { offsets[i] = excl; cursor[i] = excl; }
    if (i == N_NODES - 1) offsets[N_NODES] = excl + v;
}

// scatter: ONE int4 stream {src, dst, ewbf, perm} in perm order
__global__ __launch_bounds__(256) void scatter_kernel(
    const int* __restrict__ src, const int* __restrict__ dst,
    const float* __restrict__ ew, int* __restrict__ cursor,
    int4* __restrict__ edata) {
    int e = blockIdx.x * 256 + threadIdx.x;
    if (e < N_EDGES) {
        int d = dst[e];
        int p = atomicAdd(&cursor[d], 1);
        edata[p] = make_int4(src[e], d, (int)pk_bf16(ew[2 * e], ew[2 * e + 1]), e);
    }
}

// ===========================================================================
// Layer-d edge kernel (CIN=1): full-fp32 VALU path, perm order
// ===========================================================================
__global__ __launch_bounds__(256) void edge_d_kernel(
    const float* __restrict__ x, const int4* __restrict__ edata,
    const float* __restrict__ ew,
    const float* __restrict__ Wm1T, const float* __restrict__ bm1,
    const float* __restrict__ Wm2, const float* __restrict__ bm2,
    const float* __restrict__ W2, const float* __restrict__ b2, bf16* __restrict__ msg)
{
    int t = blockIdx.x * 256 + threadIdx.x;
    int4 ed = edata[t];
    float xi = x[ed.y], xj = x[ed.x];
    int p = ed.w;
    float e0 = ew[2 * p], e1 = ew[2 * p + 1];
    float m = bm2[0];
    for (int j = 0; j < C_MSG; ++j) {
        const float* __restrict__ wr = Wm1T + j * 4;
        float h = bm1[j];
        h = fmaf(xi, wr[0], h);
        h = fmaf(xj, wr[1], h);
        h = fmaf(e0, wr[2], h);
        h = fmaf(e1, wr[3], h);
        h = fmaxf(h, 0.f);
        m = fmaf(h, Wm2[j], m);
    }
    float md = m * (xi - xj);
    for (int o = 0; o < 15; ++o) {
        float f0 = fmaf(md, W2[2 * o], b2[2 * o]);
        float f1 = fmaf(md, W2[2 * o + 1], b2[2 * o + 1]);
        *(unsigned int*)(msg + (size_t)t * 32 + 2 * o) = pk_bf16(f0, f1);
    }
}

// ===========================================================================
// MFMA edge kernel v7: R10's v5 (single barrier) + md ALIASED into h.
// R11's 3-barrier chunking regressed (barrier serialization beat the
// occupancy gain). Here: GEMM2 of wave w reads only its OWN 16 h-rows, and
// md is written after the wave's own GEMM2 completes; GEMM3 reads only own
// md rows. So md overwrites h cols 0-31 of the wave's own rows — wave-local
// program order, no extra barrier. LDS 34816 -> 29696 B -> 5 blocks/CU
// (VGPR 64 <= 102 for 5 waves/SIMD). md stride 232 has the same bank
// pattern mod 32 as the old stride 40 (both = 20 dwords). Every MFMA and
// stored value unchanged -> bit-identical output. No dynamically-indexed
// local arrays (R9 lesson).
// ===========================================================================
template<int COUT>
__global__ __launch_bounds__(256) void edge_mfma(
    const bf16* __restrict__ xbf, const bf16* __restrict__ xlo,
    const int4* __restrict__ edata,
    const bf16* __restrict__ Wm1B, const bf16* __restrict__ SelB,
    const bf16* __restrict__ Wm2B, const bf16* __restrict__ W2B,
    bf16* __restrict__ msg)
{
    __shared__ __align__(16) char smem_all[29696];
    bf16* hp = (bf16*)smem_all;                   // [64][232]; md aliases
                                                  // own-row cols 0-31 post-GEMM2

    const int tid = threadIdx.x, w = tid >> 6, lane = tid & 63;
    const int col = lane & 15, quad = lane >> 4, row0 = quad * 4;
    const int myrow = w * 16;
    const int blk = blockIdx.x * 64;
    const int ebase = blk + myrow;

    // h pad cols [200,224) of OWN rows: col200=1 (bm2 slot), rest 0
    for (int i = lane; i < 16 * 24; i += 64) {
        int r = myrow + i / 24, c = 200 + i % 24;
        hp[r * 232 + c] = (c == 200) ? (bf16)1.f : (bf16)0.f;
    }

    // ---- own-tile fragments (for selector GEMM): separate descriptor ----
    int4 edown = edata[ebase + col];
    bf16x8 a0o = *(const bf16x8*)(xbf + (size_t)edown.y * 32 + quad * 8);
    bf16x8 a1o = *(const bf16x8*)(xbf + (size_t)edown.x * 32 + quad * 8);
    bf16x8 a2  = *(const bf16x8*)(xlo + (size_t)edown.y * 32 + quad * 8);
    bf16x8 a3  = *(const bf16x8*)(xlo + (size_t)edown.x * 32 + quad * 8);
    if (quad == 3) {
        union { unsigned int u; bf16 b[2]; } cv;
        cv.u = (unsigned int)edown.z;
        a1o[6] = cv.b[0];
        a1o[7] = cv.b[1];
    }

    // ---- A-frags for GEMM1, all 4 M-tiles (compile-time indices only) ----
    bf16x8 A0[4], A1[4];
#pragma unroll
    for (int t = 0; t < 4; ++t) {
        int4 ed = edata[blk + t * 16 + col];
        A0[t] = *(const bf16x8*)(xbf + (size_t)ed.y * 32 + quad * 8);
        A1[t] = *(const bf16x8*)(xbf + (size_t)ed.x * 32 + quad * 8);
        if (quad == 3) {
            union { unsigned int u; bf16 b[2]; } cv;
            cv.u = (unsigned int)ed.z;
            A1[t][6] = cv.b[0];
            A1[t][7] = cv.b[1];
        }
    }

    // ---- diff[16x32] = (hi_d - hi_s) + (lo_d - lo_s) via selector GEMM ----
    f32x4 dc0 = {0.f, 0.f, 0.f, 0.f}, dc1 = {0.f, 0.f, 0.f, 0.f};
    {
        bf16x8 b;
        b = *(const bf16x8*)(SelB + (size_t)0 * 512 + lane * 8);
        dc0 = __builtin_amdgcn_mfma_f32_16x16x32_bf16(a0o, b, dc0, 0, 0, 0);
        b = *(const bf16x8*)(SelB + (size_t)1 * 512 + lane * 8);
        dc1 = __builtin_amdgcn_mfma_f32_16x16x32_bf16(a0o, b, dc1, 0, 0, 0);
        b = *(const bf16x8*)(SelB + (size_t)2 * 512 + lane * 8);
        dc0 = __builtin_amdgcn_mfma_f32_16x16x32_bf16(a1o, b, dc0, 0, 0, 0);
        b = *(const bf16x8*)(SelB + (size_t)3 * 512 + lane * 8);
        dc1 = __builtin_amdgcn_mfma_f32_16x16x32_bf16(a1o, b, dc1, 0, 0, 0);
        b = *(const bf16x8*)(SelB + (size_t)4 * 512 + lane * 8);
        dc0 = __builtin_amdgcn_mfma_f32_16x16x32_bf16(a2, b, dc0, 0, 0, 0);
        b = *(const bf16x8*)(SelB + (size_t)5 * 512 + lane * 8);
        dc1 = __builtin_amdgcn_mfma_f32_16x16x32_bf16(a2, b, dc1, 0, 0, 0);
        b = *(const bf16x8*)(SelB + (size_t)6 * 512 + lane * 8);
        dc0 = __builtin_amdgcn_mfma_f32_16x16x32_bf16(a3, b, dc0, 0, 0, 0);
        b = *(const bf16x8*)(SelB + (size_t)7 * 512 + lane * 8);
        dc1 = __builtin_amdgcn_mfma_f32_16x16x32_bf16(a3, b, dc1, 0, 0, 0);
    }

    // ---- GEMM1 (N-split): this wave's pairs, all 4 A-tiles ----
    const int npair = (w < 2) ? 2 : 1;
#pragma unroll
    for (int i = 0; i < 2; ++i) {
        if (i < npair) {
            int p = (i == 0) ? w : (w + 4);
            const bf16* Wf = Wm1B + (size_t)(4 * p) * 512 + lane * 8;
            bf16x8 be0 = *(const bf16x8*)(Wf);
            bf16x8 be1 = *(const bf16x8*)(Wf + 512);
            bf16x8 bo0 = *(const bf16x8*)(Wf + 1024);
            bf16x8 bo1 = *(const bf16x8*)(Wf + 1536);
#pragma unroll
            for (int t = 0; t < 4; ++t) {
                f32x4 ae = {0.f, 0.f, 0.f, 0.f}, ao = {0.f, 0.f, 0.f, 0.f};
                ae = __builtin_amdgcn_mfma_f32_16x16x32_bf16(A0[t], be0, ae, 0, 0, 0);
                ae = __builtin_amdgcn_mfma_f32_16x16x32_bf16(A1[t], be1, ae, 0, 0, 0);
                ao = __builtin_amdgcn_mfma_f32_16x16x32_bf16(A0[t], bo0, ao, 0, 0, 0);
                ao = __builtin_amdgcn_mfma_f32_16x16x32_bf16(A1[t], bo1, ao, 0, 0, 0);
#pragma unroll
                for (int rg = 0; rg < 4; ++rg) {
                    unsigned int u = pk_bf16(fmaxf(ae[rg], 0.f), fmaxf(ao[rg], 0.f));
                    *(unsigned int*)(hp + (size_t)(t * 16 + row0 + rg) * 232 +
                                     p * 32 + 2 * col) = u;
                }
            }
        }
    }
    if (w == 2) {   // leftover N-tile 12: cols 192..199 real
        const bf16* Wf = Wm1B + (size_t)24 * 512 + lane * 8;
        bf16x8 b0 = *(const bf16x8*)(Wf);
        bf16x8 b1 = *(const bf16x8*)(Wf + 512);
#pragma unroll
        for (int t = 0; t < 4; ++t) {
            f32x4 acc = {0.f, 0.f, 0.f, 0.f};
            acc = __builtin_amdgcn_mfma_f32_16x16x32_bf16(A0[t], b0, acc, 0, 0, 0);
            acc = __builtin_amdgcn_mfma_f32_16x16x32_bf16(A1[t], b1, acc, 0, 0, 0);
            if (col < 8) {
#pragma unroll
                for (int rg = 0; rg < 4; ++rg)
                    hp[(size_t)(t * 16 + row0 + rg) * 232 + 192 + col] =
                        (bf16)fmaxf(acc[rg], 0.f);
            }
        }
    }

    __syncthreads();   // h complete block-wide

    // ---- GEMM2 on OWN 16 edges: h[16x224] @ Wm2[224x32]; md = m*diff ----
    f32x4 m0 = {0.f, 0.f, 0.f, 0.f}, m1 = {0.f, 0.f, 0.f, 0.f};
#pragma unroll
    for (int kt = 0; kt < 7; ++kt) {
        bf16x8 a = *(const bf16x8*)(hp + (size_t)(myrow + col) * 232 + kt * 32 + quad * 8);
        bf16x8 b0 = *(const bf16x8*)(Wm2B + (size_t)kt * 512 + lane * 8);
        bf16x8 b1 = *(const bf16x8*)(Wm2B + (size_t)(7 + kt) * 512 + lane * 8);
        m0 = __builtin_amdgcn_mfma_f32_16x16x32_bf16(a, b0, m0, 0, 0, 0);
        m1 = __builtin_amdgcn_mfma_f32_16x16x32_bf16(a, b1, m1, 0, 0, 0);
    }
    // md overwrites OWN h rows, cols 0-31 (dead after own GEMM2; wave-local)
#pragma unroll
    for (int rg = 0; rg < 4; ++rg) {
        unsigned int u = (col == 15) ? pk_bf16(1.f, 0.f)
                                     : pk_bf16(m0[rg] * dc0[rg], m1[rg] * dc1[rg]);
        *(unsigned int*)(hp + (size_t)(myrow + row0 + rg) * 232 + 2 * col) = u;
    }

    // ---- GEMM3: md[16x32] @ W2[32xN] -> msg (wave-local) ----
    bf16x8 am = *(const bf16x8*)(hp + (size_t)(myrow + col) * 232 + quad * 8);
    if (COUT == 30) {
        bf16x8 b0 = *(const bf16x8*)(W2B + lane * 8);
        bf16x8 b1 = *(const bf16x8*)(W2B + 512 + lane * 8);
        f32x4 c0 = {0.f, 0.f, 0.f, 0.f}, c1 = {0.f, 0.f, 0.f, 0.f};
        c0 = __builtin_amdgcn_mfma_f32_16x16x32_bf16(am, b0, c0, 0, 0, 0);
        c1 = __builtin_amdgcn_mfma_f32_16x16x32_bf16(am, b1, c1, 0, 0, 0);
#pragma unroll
        for (int rg = 0; rg < 4; ++rg)
            *(unsigned int*)(msg + (size_t)(ebase + row0 + rg) * 32 + 2 * col) =
                pk_bf16(c0[rg], c1[rg]);
    } else {
        bf16x8 b0 = *(const bf16x8*)(W2B + lane * 8);
        f32x4 c0 = {0.f, 0.f, 0.f, 0.f};
        c0 = __builtin_amdgcn_mfma_f32_16x16x32_bf16(am, b0, c0, 0, 0, 0);
        if (col == 0) {
#pragma unroll
            for (int rg = 0; rg < 4; ++rg)
                msg[(size_t)(ebase + row0 + rg) * 32] = (bf16)c0[rg];
        }
    }
}

// ===========================================================================
// Fused aggregation + next node term. 16 lanes per node; width-16 shuffles;
// fma order identical to the original node_kernel -> numerically identical.
// ===========================================================================
template<int CNEXT>
__global__ __launch_bounds__(256) void agg_fused(
    const bf16* __restrict__ msg, const int* __restrict__ offsets,
    const float* __restrict__ bufc,
    const float* __restrict__ W1n, const float* __restrict__ b1n,
    float* __restrict__ bufn,
    bf16* __restrict__ xbf, bf16* __restrict__ xlo) {
    int gh = (blockIdx.x * 256 + threadIdx.x) >> 4;
    int lane = threadIdx.x & 15;
    int s0 = offsets[gh], s1 = offsets[gh + 1];
    float r0 = 0.f, r1 = 0.f;
    if (lane < 15) {
        float v0 = 0.f, v1 = 0.f;
        const unsigned int* mp =
            (const unsigned int*)(msg + (size_t)s0 * 32 + lane * 2);
        int cnt = s1 - s0, j = 0;
        for (; j + 4 <= cnt; j += 4) {
            unsigned int u0 = mp[(size_t)(j + 0) * 16];
            unsigned int u1 = mp[(size_t)(j + 1) * 16];
            unsigned int u2 = mp[(size_t)(j + 2) * 16];
            unsigned int u3 = mp[(size_t)(j + 3) * 16];
            union { unsigned int u; bf16 b[2]; } c0, c1, c2, c3;
            c0.u = u0; c1.u = u1; c2.u = u2; c3.u = u3;
            v0 += (float)c0.b[0]; v1 += (float)c0.b[1];
            v0 += (float)c1.b[0]; v1 += (float)c1.b[1];
            v0 += (float)c2.b[0]; v1 += (float)c2.b[1];
            v0 += (float)c3.b[0]; v1 += (float)c3.b[1];
        }
        for (; j < cnt; ++j) {
            union { unsigned int u; bf16 b[2]; } cv;
            cv.u = mp[(size_t)j * 16];
            v0 += (float)cv.b[0]; v1 += (float)cv.b[1];
        }
        float f0 = bufc[(size_t)gh * 30 + 2 * lane] + v0;
        float f1 = bufc[(size_t)gh * 30 + 2 * lane + 1] + v1;
        r0 = fmaxf(f0, 0.f);
        r1 = fmaxf(f1, 0.f);
        bf16 h0 = (bf16)r0, h1 = (bf16)r1;
        union { bf16 h[2]; unsigned int u; } hi;
        hi.h[0] = h0; hi.h[1] = h1;
        *(unsigned int*)(xbf + (size_t)gh * 32 + 2 * lane) = hi.u;
        *(unsigned int*)(xlo + (size_t)gh * 32 + 2 * lane) =
            pk_bf16(r0 - (float)h0, r1 - (float)h1);
    } else {
        *(unsigned int*)(xbf + (size_t)gh * 32 + 30) = pk_bf16(1.f, 0.f);
        *(unsigned int*)(xlo + (size_t)gh * 32 + 30) = 0u;
    }
    // ---- next node term (fma order == original node_kernel) ----
    if (CNEXT == 30) {
        float acc0 = 0.f, acc1 = 0.f;
        if (lane < 15) { acc0 = b1n[2 * lane]; acc1 = b1n[2 * lane + 1]; }
        for (int k2 = 0; k2 < 15; ++k2) {
            float rk0 = __shfl(r0, k2, 16);
            float rk1 = __shfl(r1, k2, 16);
            if (lane < 15) {
                const float* w0 = W1n + (2 * k2) * 30 + 2 * lane;
                const float* w1 = W1n + (2 * k2 + 1) * 30 + 2 * lane;
                acc0 = fmaf(rk0, w0[0], acc0);
                acc1 = fmaf(rk0, w0[1], acc1);
                acc0 = fmaf(rk1, w1[0], acc0);
                acc1 = fmaf(rk1, w1[1], acc1);
            }
        }
        if (lane < 15) {
            bufn[(size_t)gh * 30 + 2 * lane] = acc0;
            bufn[(size_t)gh * 30 + 2 * lane + 1] = acc1;
        }
    } else {
        float acc = b1n[0];
        for (int k2 = 0; k2 < 15; ++k2) {
            float rk0 = __shfl(r0, k2, 16);
            float rk1 = __shfl(r1, k2, 16);
            acc = fmaf(rk0, W1n[2 * k2], acc);
            acc = fmaf(rk1, W1n[2 * k2 + 1], acc);
        }
        if (lane == 0) bufn[gh] = acc;
    }
}

// Final aggregation (msg COUT=1): out[gh] += msgsum
__global__ __launch_bounds__(256) void agg_last(const bf16* __restrict__ msg,
                                                const int* __restrict__ offsets,
                                                float* __restrict__ out) {
    int gh = (blockIdx.x * 256 + threadIdx.x) >> 5;
    int lane = threadIdx.x & 31;
    int s0 = offsets[gh], s1 = offsets[gh + 1];
    float v = 0.f;
    for (int j = s0 + lane; j < s1; j += 32) v += (float)msg[(size_t)j * 32];
#pragma unroll
    for (int o = 16; o > 0; o >>= 1) v += __shfl_xor(v, o);
    if (lane == 0) out[gh] += v;
}

// ===========================================================================
extern "C" void kernel_launch(void* const* d_in, const int* in_sizes, int n_in,
                              void* d_out, int out_size, void* d_ws, size_t ws_size,
                              hipStream_t stream) {
    const float* features = (const float*)d_in[0];
    const int*   edges    = (const int*)d_in[1];
    const float* ew       = (const float*)d_in[2];

    const float* W1_d  = (const float*)d_in[3];
    const float* b1_d  = (const float*)d_in[4];
    const float* Wm1_d = (const float*)d_in[5];
    const float* bm1_d = (const float*)d_in[6];
    const float* Wm2_d = (const float*)d_in[7];
    const float* bm2_d = (const float*)d_in[8];
    const float* W2_d  = (const float*)d_in[9];
    const float* b2_d  = (const float*)d_in[10];

    const float* W1_h  = (const float*)d_in[11];
    const float* b1_h  = (const float*)d_in[12];
    const float* Wm1_h = (const float*)d_in[13];
    const float* bm1_h = (const float*)d_in[14];
    const float* Wm2_h = (const float*)d_in[15];
    const float* bm2_h = (const float*)d_in[16];
    const float* W2_h  = (const float*)d_in[17];
    const float* b2_h  = (const float*)d_in[18];

    const float* W1_o  = (const float*)d_in[19];
    const float* b1_o  = (const float*)d_in[20];
    const float* Wm1_o = (const float*)d_in[21];
    const float* bm1_o = (const float*)d_in[22];
    const float* Wm2_o = (const float*)d_in[23];
    const float* bm2_o = (const float*)d_in[24];
    const float* W2_o  = (const float*)d_in[25];
    const float* b2_o  = (const float*)d_in[26];

    const int* src = edges;
    const int* dst = edges + N_EDGES;
    float* out = (float*)d_out;

    // ---- workspace carve-up ----
    char* p = (char*)d_ws;
    auto alloc = [&](size_t bytes) { char* r = p; p += (bytes + 63) & ~(size_t)63; return r; };
    float* bufA    = (float*)alloc((size_t)N_NODES * 30 * 4);
    float* bufB    = (float*)alloc((size_t)N_NODES * 30 * 4);
    bf16*  msg     = (bf16*) alloc((size_t)N_EDGES * 32 * 2);
    bf16*  xbf     = (bf16*) alloc((size_t)N_NODES * 32 * 2);
    bf16*  xlo     = (bf16*) alloc((size_t)N_NODES * 32 * 2);
    int*   counts  = (int*)  alloc((size_t)N_NODES * 4);
    int*   offsets = (int*)  alloc((size_t)(N_NODES + 1) * 4);
    int*   cursor  = (int*)  alloc((size_t)N_NODES * 4);
    int4*  edata   = (int4*) alloc((size_t)N_EDGES * 16);
    float* Wm1T_d  = (float*)alloc((size_t)C_MSG * 4 * 4);
    bf16*  Wm1B_h  = (bf16*) alloc((size_t)26 * 512 * 2);
    bf16*  Wm1B_o  = (bf16*) alloc((size_t)26 * 512 * 2);
    bf16*  Wm2B_h  = (bf16*) alloc((size_t)14 * 512 * 2);
    bf16*  Wm2B_o  = (bf16*) alloc((size_t)14 * 512 * 2);
    bf16*  W2B_h   = (bf16*) alloc((size_t)2 * 512 * 2);
    bf16*  W2B_o   = (bf16*) alloc((size_t)1 * 512 * 2);
    bf16*  SelB    = (bf16*) alloc((size_t)8 * 512 * 2);

    // ---- setup ----
    hipMemsetAsync(counts, 0, (size_t)N_NODES * 4, stream);
    setup_a<<<3507, 256, 0, stream>>>(dst, counts,
        Wm1_h, bm1_h, Wm1_o, bm1_o, Wm2_h, bm2_h, Wm2_o, bm2_o,
        W2_h, b2_h, W2_o, b2_o, Wm1_d,
        Wm1B_h, Wm1B_o, Wm2B_h, Wm2B_o, W2B_h, W2B_o, SelB, Wm1T_d,
        features, W1_d, b1_d, bufA);
    scan_kernel<<<(N_NODES + 255) / 256, 256, 0, stream>>>(counts, offsets, cursor);
    scatter_kernel<<<N_EDGES / 256, 256, 0, stream>>>(src, dst, ew, cursor, edata);

    dim3 tb(256);
    dim3 eb_mfma(N_EDGES / 64);
    dim3 eb_valu(N_EDGES / 256);
    dim3 ab16(N_NODES * 16 / 256);
    dim3 ab32(N_NODES * 32 / 256);

    // ---- layer d ----
    edge_d_kernel<<<eb_valu, tb, 0, stream>>>(features, edata, ew,
        Wm1T_d, bm1_d, Wm2_d, bm2_d, W2_d, b2_d, msg);
    agg_fused<30><<<ab16, tb, 0, stream>>>(msg, offsets, bufA, W1_h, b1_h, bufB, xbf, xlo);

    // ---- h1 ----
    edge_mfma<30><<<eb_mfma, tb, 0, stream>>>(xbf, xlo, edata,
        Wm1B_h, SelB, Wm2B_h, W2B_h, msg);
    agg_fused<30><<<ab16, tb, 0, stream>>>(msg, offsets, bufB, W1_h, b1_h, bufA, xbf, xlo);

    // ---- h2 ----
    edge_mfma<30><<<eb_mfma, tb, 0, stream>>>(xbf, xlo, edata,
        Wm1B_h, SelB, Wm2B_h, W2B_h, msg);
    agg_fused<30><<<ab16, tb, 0, stream>>>(msg, offsets, bufA, W1_h, b1_h, bufB, xbf, xlo);

    // ---- h3 (next node term = output layer -> writes d_out) ----
    edge_mfma<30><<<eb_mfma, tb, 0, stream>>>(xbf, xlo, edata,
        Wm1B_h, SelB, Wm2B_h, W2B_h, msg);
    agg_fused<1><<<ab16, tb, 0, stream>>>(msg, offsets, bufB, W1_o, b1_o, out, xbf, xlo);

    // ---- output layer ----
    edge_mfma<1><<<eb_mfma, tb, 0, stream>>>(xbf, xlo, edata,
        Wm1B_o, SelB, Wm2B_o, W2B_o, msg);
    agg_last<<<ab32, tb, 0, stream>>>(msg, offsets, out);
}

// Round 13
// 754.816 us; speedup vs baseline: 1.0698x; 1.0092x over previous
//
#include <hip/hip_runtime.h>

#define N_NODES 50000
#define N_EDGES 800000
#define C_MSG 200

typedef __bf16 bf16;
typedef __attribute__((ext_vector_type(8))) __bf16 bf16x8;
typedef __attribute__((ext_vector_type(4))) float f32x4;

static __device__ __forceinline__ unsigned int pk_bf16(float a, float b) {
    union { bf16 h[2]; unsigned int u; } cv;
    cv.h[0] = (bf16)a; cv.h[1] = (bf16)b;
    return cv.u;
}

// ===========================================================================
// Weight packers (device fns) -> MFMA B-frag order (16x16x32), biases folded.
// Fragment f at out[f*512 + lane*8 + i]; lane holds B[k][n], k=kt*32+(lane>>4)*8+i.
// Paired N-tiles: pair p covers cols p*32 + 2*(lane&15) + parity.
// ===========================================================================
static __device__ void dev_pack_wm1(int tid, const float* W, const float* bm1,
                                    bf16* out) {
    int i = tid & 7, lane = (tid >> 3) & 63, rest = tid >> 9;
    int kt = rest % 2, t = rest / 2;
    int k = kt * 32 + ((lane >> 4) * 8) + i;
    int c = lane & 15;
    int n = (t < 12) ? ((t >> 1) * 32 + 2 * c + (t & 1)) : (192 + c);
    float v = 0.f;
    if (n < C_MSG) {
        if (k < 30)       v = W[k * C_MSG + n];
        else if (k == 30) v = bm1[n];
        else if (k >= 32) v = W[(k - 2) * C_MSG + n];
    }
    out[tid] = (bf16)v;
}

static __device__ void dev_pack_wm2(int tid, const float* W, const float* bm2,
                                    bf16* out) {
    int i = tid & 7, lane = (tid >> 3) & 63, rest = tid >> 9;
    int kt = rest % 7, nt = rest / 7;
    int k = kt * 32 + ((lane >> 4) * 8) + i;
    int n = 2 * (lane & 15) + nt;
    float v = 0.f;
    if (n < 30) {
        if (k < C_MSG)       v = W[k * 30 + n];
        else if (k == C_MSG) v = bm2[n];
    }
    out[tid] = (bf16)v;
}

static __device__ void dev_pack_w2h(int tid, const float* W, const float* b2,
                                    bf16* out) {
    int i = tid & 7, lane = (tid >> 3) & 63, nt = tid >> 9;
    int k = ((lane >> 4) * 8) + i;
    int n = 2 * (lane & 15) + nt;
    float v = 0.f;
    if (n < 30) {
        if (k < 30)       v = W[k * 30 + n];
        else if (k == 30) v = b2[n];
    }
    out[tid] = (bf16)v;
}

static __device__ void dev_pack_w2o(int tid, const float* W, const float* b2,
                                    bf16* out) {
    int i = tid & 7, lane = (tid >> 3) & 63;
    int k = ((lane >> 4) * 8) + i;
    int n = lane & 15;
    float v = 0.f;
    if (n == 0) {
        if (k < 30)       v = W[k];
        else if (k == 30) v = b2[0];
    }
    out[tid] = (bf16)v;
}

static __device__ void dev_pack_sel(int tid, bf16* out) {
    int i = tid & 7, lane = (tid >> 3) & 63, f = tid >> 9;
    int kt = f >> 1, nt = f & 1;
    int kloc = ((lane >> 4) * 8) + i;
    int n = 2 * (lane & 15) + nt;
    float v = (kloc == n && n < 30) ? ((kt & 1) ? -1.f : 1.f) : 0.f;
    out[tid] = (bf16)v;
}

// ===========================================================================
// setup_a: count (3125 blocks) + pack_all (186) + node_d (196) in ONE dispatch
// ===========================================================================
__global__ __launch_bounds__(256) void setup_a(
    const int* __restrict__ dst, int* __restrict__ counts,
    const float* __restrict__ Wm1_h, const float* __restrict__ bm1_h,
    const float* __restrict__ Wm1_o, const float* __restrict__ bm1_o,
    const float* __restrict__ Wm2_h, const float* __restrict__ bm2_h,
    const float* __restrict__ Wm2_o, const float* __restrict__ bm2_o,
    const float* __restrict__ W2_h,  const float* __restrict__ b2_h,
    const float* __restrict__ W2_o,  const float* __restrict__ b2_o,
    const float* __restrict__ Wm1_d,
    bf16* __restrict__ Wm1B_h, bf16* __restrict__ Wm1B_o,
    bf16* __restrict__ Wm2B_h, bf16* __restrict__ Wm2B_o,
    bf16* __restrict__ W2B_h,  bf16* __restrict__ W2B_o,
    bf16* __restrict__ SelB,   float* __restrict__ Wm1T_d,
    const float* __restrict__ features, const float* __restrict__ W1_d,
    const float* __restrict__ b1_d, float* __restrict__ bufA) {
    int b = blockIdx.x, t = threadIdx.x;
    if (b < 3125) {                                  // count
        int e = b * 256 + t;
        if (e < N_EDGES) atomicAdd(&counts[dst[e]], 1);
    } else if (b < 3311) {                           // pack_all
        int pb = b - 3125;
        if (pb < 52)       dev_pack_wm1(pb * 256 + t, Wm1_h, bm1_h, Wm1B_h);
        else if (pb < 104) dev_pack_wm1((pb - 52) * 256 + t, Wm1_o, bm1_o, Wm1B_o);
        else if (pb < 132) dev_pack_wm2((pb - 104) * 256 + t, Wm2_h, bm2_h, Wm2B_h);
        else if (pb < 160) dev_pack_wm2((pb - 132) * 256 + t, Wm2_o, bm2_o, Wm2B_o);
        else if (pb < 164) dev_pack_w2h((pb - 160) * 256 + t, W2_h, b2_h, W2B_h);
        else if (pb < 166) dev_pack_w2o((pb - 164) * 256 + t, W2_o, b2_o, W2B_o);
        else if (pb < 182) dev_pack_sel((pb - 166) * 256 + t, SelB);
        else {
            int i = (pb - 182) * 256 + t;
            if (i < C_MSG * 4) Wm1T_d[i] = Wm1_d[(i & 3) * C_MSG + (i >> 2)];
        }
    } else {                                         // node term, layer d
        int n = (b - 3311) * 256 + t;
        if (n < N_NODES) {
            float xv = features[n];
            for (int o = 0; o < 30; ++o)
                bufA[n * 30 + o] = fmaf(xv, W1_d[o], b1_d[o]);
        }
    }
}

// Parallel scan over counts
__global__ __launch_bounds__(256) void scan_kernel(const int* __restrict__ counts,
                                                   int* __restrict__ offsets,
                                                   int* __restrict__ cursor) {
    __shared__ int ws[4];
    const int b = blockIdx.x, t = threadIdx.x;
    const int lane = t & 63, wv = t >> 6;
    int acc = 0;
    for (int i = t; i < b * 256; i += 256) acc += counts[i];
#pragma unroll
    for (int d = 32; d > 0; d >>= 1) acc += __shfl_xor(acc, d);
    if (lane == 0) ws[wv] = acc;
    __syncthreads();
    int base = ws[0] + ws[1] + ws[2] + ws[3];
    __syncthreads();
    int i = b * 256 + t;
    int v = (i < N_NODES) ? counts[i] : 0;
    int inc = v;
#pragma unroll
    for (int d = 1; d < 64; d <<= 1) {
        int u = __shfl_up(inc, d);
        if (lane >= d) inc += u;
    }
    if (lane == 63) ws[wv] = inc;
    __syncthreads();
    int waveoff = 0;
    for (int k = 0; k < wv; ++k) waveoff += ws[k];
    int excl = base + waveoff + inc - v;
    if (i < N_NODES) { offsets[i] = excl; cursor[i] = excl; }
    if (i == N_NODES - 1) offsets[N_NODES] = excl + v;
}

// scatter: ONE int4 stream {src, dst, ewbf, perm} in perm order
__global__ __launch_bounds__(256) void scatter_kernel(
    const int* __restrict__ src, const int* __restrict__ dst,
    const float* __restrict__ ew, int* __restrict__ cursor,
    int4* __restrict__ edata) {
    int e = blockIdx.x * 256 + threadIdx.x;
    if (e < N_EDGES) {
        int d = dst[e];
        int p = atomicAdd(&cursor[d], 1);
        edata[p] = make_int4(src[e], d, (int)pk_bf16(ew[2 * e], ew[2 * e + 1]), e);
    }
}

// ===========================================================================
// Layer-d edge kernel (CIN=1): full-fp32 VALU path, perm order
// ===========================================================================
__global__ __launch_bounds__(256) void edge_d_kernel(
    const float* __restrict__ x, const int4* __restrict__ edata,
    const float* __restrict__ ew,
    const float* __restrict__ Wm1T, const float* __restrict__ bm1,
    const float* __restrict__ Wm2, const float* __restrict__ bm2,
    const float* __restrict__ W2, const float* __restrict__ b2, bf16* __restrict__ msg)
{
    int t = blockIdx.x * 256 + threadIdx.x;
    int4 ed = edata[t];
    float xi = x[ed.y], xj = x[ed.x];
    int p = ed.w;
    float e0 = ew[2 * p], e1 = ew[2 * p + 1];
    float m = bm2[0];
    for (int j = 0; j < C_MSG; ++j) {
        const float* __restrict__ wr = Wm1T + j * 4;
        float h = bm1[j];
        h = fmaf(xi, wr[0], h);
        h = fmaf(xj, wr[1], h);
        h = fmaf(e0, wr[2], h);
        h = fmaf(e1, wr[3], h);
        h = fmaxf(h, 0.f);
        m = fmaf(h, Wm2[j], m);
    }
    float md = m * (xi - xj);
    for (int o = 0; o < 15; ++o) {
        float f0 = fmaf(md, W2[2 * o], b2[2 * o]);
        float f1 = fmaf(md, W2[2 * o + 1], b2[2 * o + 1]);
        *(unsigned int*)(msg + (size_t)t * 32 + 2 * o) = pk_bf16(f0, f1);
    }
}

// ===========================================================================
// MFMA edge kernel v8: v7 (single barrier, md aliased into h) with
// instruction trims — the kernel is ISSUE-bound (R10-R12 evidence:
// occupancy changes didn't move dur; VALU 43% + MFMA 15% + LDS/VMEM ~sat).
// Trims (all value-preserving):
//  (1) own-tile descriptor merged into the A-frag loop via literal-index
//      `if (t == w)` (wave-uniform; no dynamic local indexing — R9 lesson):
//      -3 global loads, -~15 VALU. a1o == A1[w] incl. ew patch (selector
//      rows 30/31 of kt1 are zero -> patch never reaches the diff).
//  (2) h-pad init as 48x ds_write_b128 of a constant vector (was 6-iter
//      div-by-24 loop): -~30 VALU, -5 DS ops.
//  (3) COUT=1: compact msg1[e] stores (was msg[e*32]: 1 bf16 per 64B line,
//      ~50 MB write amplification for 1.6 MB of data).
// Bit-identical output.
// ===========================================================================
template<int COUT>
__global__ __launch_bounds__(256) void edge_mfma(
    const bf16* __restrict__ xbf, const bf16* __restrict__ xlo,
    const int4* __restrict__ edata,
    const bf16* __restrict__ Wm1B, const bf16* __restrict__ SelB,
    const bf16* __restrict__ Wm2B, const bf16* __restrict__ W2B,
    bf16* __restrict__ msg)
{
    __shared__ __align__(16) char smem_all[29696];
    bf16* hp = (bf16*)smem_all;                   // [64][232]; md aliases
                                                  // own-row cols 0-31 post-GEMM2

    const int tid = threadIdx.x, w = tid >> 6, lane = tid & 63;
    const int col = lane & 15, quad = lane >> 4, row0 = quad * 4;
    const int myrow = w * 16;
    const int blk = blockIdx.x * 64;
    const int ebase = blk + myrow;

    // h pad cols [200,224) of OWN rows: col200=1 (bm2 slot), rest 0.
    // 16 rows x 24 cols = 48 b128 chunks; lane<48 writes one.
    if (lane < 48) {
        int r = lane / 3, ch = lane - r * 3;
        bf16x8 z = {};
        if (ch == 0) z[0] = (bf16)1.f;
        *(bf16x8*)(hp + (myrow + r) * 232 + 200 + ch * 8) = z;
    }

    // ---- A-frags for GEMM1 (all 4 M-tiles) + own-tile extraction ----
    bf16x8 A0[4], A1[4], a0o, a1o, a2, a3;
#pragma unroll
    for (int t = 0; t < 4; ++t) {
        int4 ed = edata[blk + t * 16 + col];
        A0[t] = *(const bf16x8*)(xbf + ed.y * 32 + quad * 8);
        A1[t] = *(const bf16x8*)(xbf + ed.x * 32 + quad * 8);
        if (quad == 3) {
            union { unsigned int u; bf16 b[2]; } cv;
            cv.u = (unsigned int)ed.z;
            A1[t][6] = cv.b[0];
            A1[t][7] = cv.b[1];
        }
        if (t == w) {                    // wave-uniform; t is a literal
            a0o = A0[t];
            a1o = A1[t];
            a2 = *(const bf16x8*)(xlo + ed.y * 32 + quad * 8);
            a3 = *(const bf16x8*)(xlo + ed.x * 32 + quad * 8);
        }
    }

    // ---- diff[16x32] = (hi_d - hi_s) + (lo_d - lo_s) via selector GEMM ----
    f32x4 dc0 = {0.f, 0.f, 0.f, 0.f}, dc1 = {0.f, 0.f, 0.f, 0.f};
    {
        bf16x8 b;
        b = *(const bf16x8*)(SelB + (size_t)0 * 512 + lane * 8);
        dc0 = __builtin_amdgcn_mfma_f32_16x16x32_bf16(a0o, b, dc0, 0, 0, 0);
        b = *(const bf16x8*)(SelB + (size_t)1 * 512 + lane * 8);
        dc1 = __builtin_amdgcn_mfma_f32_16x16x32_bf16(a0o, b, dc1, 0, 0, 0);
        b = *(const bf16x8*)(SelB + (size_t)2 * 512 + lane * 8);
        dc0 = __builtin_amdgcn_mfma_f32_16x16x32_bf16(a1o, b, dc0, 0, 0, 0);
        b = *(const bf16x8*)(SelB + (size_t)3 * 512 + lane * 8);
        dc1 = __builtin_amdgcn_mfma_f32_16x16x32_bf16(a1o, b, dc1, 0, 0, 0);
        b = *(const bf16x8*)(SelB + (size_t)4 * 512 + lane * 8);
        dc0 = __builtin_amdgcn_mfma_f32_16x16x32_bf16(a2, b, dc0, 0, 0, 0);
        b = *(const bf16x8*)(SelB + (size_t)5 * 512 + lane * 8);
        dc1 = __builtin_amdgcn_mfma_f32_16x16x32_bf16(a2, b, dc1, 0, 0, 0);
        b = *(const bf16x8*)(SelB + (size_t)6 * 512 + lane * 8);
        dc0 = __builtin_amdgcn_mfma_f32_16x16x32_bf16(a3, b, dc0, 0, 0, 0);
        b = *(const bf16x8*)(SelB + (size_t)7 * 512 + lane * 8);
        dc1 = __builtin_amdgcn_mfma_f32_16x16x32_bf16(a3, b, dc1, 0, 0, 0);
    }

    // ---- GEMM1 (N-split): this wave's pairs, all 4 A-tiles ----
    const int npair = (w < 2) ? 2 : 1;
#pragma unroll
    for (int i = 0; i < 2; ++i) {
        if (i < npair) {
            int p = (i == 0) ? w : (w + 4);
            const bf16* Wf = Wm1B + (size_t)(4 * p) * 512 + lane * 8;
            bf16x8 be0 = *(const bf16x8*)(Wf);
            bf16x8 be1 = *(const bf16x8*)(Wf + 512);
            bf16x8 bo0 = *(const bf16x8*)(Wf + 1024);
            bf16x8 bo1 = *(const bf16x8*)(Wf + 1536);
#pragma unroll
            for (int t = 0; t < 4; ++t) {
                f32x4 ae = {0.f, 0.f, 0.f, 0.f}, ao = {0.f, 0.f, 0.f, 0.f};
                ae = __builtin_amdgcn_mfma_f32_16x16x32_bf16(A0[t], be0, ae, 0, 0, 0);
                ae = __builtin_amdgcn_mfma_f32_16x16x32_bf16(A1[t], be1, ae, 0, 0, 0);
                ao = __builtin_amdgcn_mfma_f32_16x16x32_bf16(A0[t], bo0, ao, 0, 0, 0);
                ao = __builtin_amdgcn_mfma_f32_16x16x32_bf16(A1[t], bo1, ao, 0, 0, 0);
#pragma unroll
                for (int rg = 0; rg < 4; ++rg) {
                    unsigned int u = pk_bf16(fmaxf(ae[rg], 0.f), fmaxf(ao[rg], 0.f));
                    *(unsigned int*)(hp + (t * 16 + row0 + rg) * 232 +
                                     p * 32 + 2 * col) = u;
                }
            }
        }
    }
    if (w == 2) {   // leftover N-tile 12: cols 192..199 real
        const bf16* Wf = Wm1B + (size_t)24 * 512 + lane * 8;
        bf16x8 b0 = *(const bf16x8*)(Wf);
        bf16x8 b1 = *(const bf16x8*)(Wf + 512);
#pragma unroll
        for (int t = 0; t < 4; ++t) {
            f32x4 acc = {0.f, 0.f, 0.f, 0.f};
            acc = __builtin_amdgcn_mfma_f32_16x16x32_bf16(A0[t], b0, acc, 0, 0, 0);
            acc = __builtin_amdgcn_mfma_f32_16x16x32_bf16(A1[t], b1, acc, 0, 0, 0);
            if (col < 8) {
#pragma unroll
                for (int rg = 0; rg < 4; ++rg)
                    hp[(t * 16 + row0 + rg) * 232 + 192 + col] =
                        (bf16)fmaxf(acc[rg], 0.f);
            }
        }
    }

    __syncthreads();   // h complete block-wide

    // ---- GEMM2 on OWN 16 edges: h[16x224] @ Wm2[224x32]; md = m*diff ----
    f32x4 m0 = {0.f, 0.f, 0.f, 0.f}, m1 = {0.f, 0.f, 0.f, 0.f};
#pragma unroll
    for (int kt = 0; kt < 7; ++kt) {
        bf16x8 a = *(const bf16x8*)(hp + (myrow + col) * 232 + kt * 32 + quad * 8);
        bf16x8 b0 = *(const bf16x8*)(Wm2B + (size_t)kt * 512 + lane * 8);
        bf16x8 b1 = *(const bf16x8*)(Wm2B + (size_t)(7 + kt) * 512 + lane * 8);
        m0 = __builtin_amdgcn_mfma_f32_16x16x32_bf16(a, b0, m0, 0, 0, 0);
        m1 = __builtin_amdgcn_mfma_f32_16x16x32_bf16(a, b1, m1, 0, 0, 0);
    }
    // md overwrites OWN h rows, cols 0-31 (dead after own GEMM2; wave-local)
#pragma unroll
    for (int rg = 0; rg < 4; ++rg) {
        unsigned int u = (col == 15) ? pk_bf16(1.f, 0.f)
                                     : pk_bf16(m0[rg] * dc0[rg], m1[rg] * dc1[rg]);
        *(unsigned int*)(hp + (myrow + row0 + rg) * 232 + 2 * col) = u;
    }

    // ---- GEMM3: md[16x32] @ W2[32xN] -> msg (wave-local) ----
    bf16x8 am = *(const bf16x8*)(hp + (myrow + col) * 232 + quad * 8);
    if (COUT == 30) {
        bf16x8 b0 = *(const bf16x8*)(W2B + lane * 8);
        bf16x8 b1 = *(const bf16x8*)(W2B + 512 + lane * 8);
        f32x4 c0 = {0.f, 0.f, 0.f, 0.f}, c1 = {0.f, 0.f, 0.f, 0.f};
        c0 = __builtin_amdgcn_mfma_f32_16x16x32_bf16(am, b0, c0, 0, 0, 0);
        c1 = __builtin_amdgcn_mfma_f32_16x16x32_bf16(am, b1, c1, 0, 0, 0);
#pragma unroll
        for (int rg = 0; rg < 4; ++rg)
            *(unsigned int*)(msg + (size_t)(ebase + row0 + rg) * 32 + 2 * col) =
                pk_bf16(c0[rg], c1[rg]);
    } else {
        // COUT=1: compact msg1[e] layout — one 8B store per col==0 lane
        bf16x8 b0 = *(const bf16x8*)(W2B + lane * 8);
        f32x4 c0 = {0.f, 0.f, 0.f, 0.f};
        c0 = __builtin_amdgcn_mfma_f32_16x16x32_bf16(am, b0, c0, 0, 0, 0);
        if (col == 0) {
            union { bf16 h[4]; unsigned long long u; } pk4;
#pragma unroll
            for (int rg = 0; rg < 4; ++rg) pk4.h[rg] = (bf16)c0[rg];
            *(unsigned long long*)(msg + (ebase + row0)) = pk4.u;
        }
    }
}

// ===========================================================================
// Fused aggregation + next node term. 16 lanes per node; width-16 shuffles;
// fma order identical to the original node_kernel -> numerically identical.
// ===========================================================================
template<int CNEXT>
__global__ __launch_bounds__(256) void agg_fused(
    const bf16* __restrict__ msg, const int* __restrict__ offsets,
    const float* __restrict__ bufc,
    const float* __restrict__ W1n, const float* __restrict__ b1n,
    float* __restrict__ bufn,
    bf16* __restrict__ xbf, bf16* __restrict__ xlo) {
    int gh = (blockIdx.x * 256 + threadIdx.x) >> 4;
    int lane = threadIdx.x & 15;
    int s0 = offsets[gh], s1 = offsets[gh + 1];
    float r0 = 0.f, r1 = 0.f;
    if (lane < 15) {
        float v0 = 0.f, v1 = 0.f;
        const unsigned int* mp =
            (const unsigned int*)(msg + (size_t)s0 * 32 + lane * 2);
        int cnt = s1 - s0, j = 0;
        for (; j + 4 <= cnt; j += 4) {
            unsigned int u0 = mp[(size_t)(j + 0) * 16];
            unsigned int u1 = mp[(size_t)(j + 1) * 16];
            unsigned int u2 = mp[(size_t)(j + 2) * 16];
            unsigned int u3 = mp[(size_t)(j + 3) * 16];
            union { unsigned int u; bf16 b[2]; } c0, c1, c2, c3;
            c0.u = u0; c1.u = u1; c2.u = u2; c3.u = u3;
            v0 += (float)c0.b[0]; v1 += (float)c0.b[1];
            v0 += (float)c1.b[0]; v1 += (float)c1.b[1];
            v0 += (float)c2.b[0]; v1 += (float)c2.b[1];
            v0 += (float)c3.b[0]; v1 += (float)c3.b[1];
        }
        for (; j < cnt; ++j) {
            union { unsigned int u; bf16 b[2]; } cv;
            cv.u = mp[(size_t)j * 16];
            v0 += (float)cv.b[0]; v1 += (float)cv.b[1];
        }
        float f0 = bufc[(size_t)gh * 30 + 2 * lane] + v0;
        float f1 = bufc[(size_t)gh * 30 + 2 * lane + 1] + v1;
        r0 = fmaxf(f0, 0.f);
        r1 = fmaxf(f1, 0.f);
        bf16 h0 = (bf16)r0, h1 = (bf16)r1;
        union { bf16 h[2]; unsigned int u; } hi;
        hi.h[0] = h0; hi.h[1] = h1;
        *(unsigned int*)(xbf + (size_t)gh * 32 + 2 * lane) = hi.u;
        *(unsigned int*)(xlo + (size_t)gh * 32 + 2 * lane) =
            pk_bf16(r0 - (float)h0, r1 - (float)h1);
    } else {
        *(unsigned int*)(xbf + (size_t)gh * 32 + 30) = pk_bf16(1.f, 0.f);
        *(unsigned int*)(xlo + (size_t)gh * 32 + 30) = 0u;
    }
    // ---- next node term (fma order == original node_kernel) ----
    if (CNEXT == 30) {
        float acc0 = 0.f, acc1 = 0.f;
        if (lane < 15) { acc0 = b1n[2 * lane]; acc1 = b1n[2 * lane + 1]; }
        for (int k2 = 0; k2 < 15; ++k2) {
            float rk0 = __shfl(r0, k2, 16);
            float rk1 = __shfl(r1, k2, 16);
            if (lane < 15) {
                const float* w0 = W1n + (2 * k2) * 30 + 2 * lane;
                const float* w1 = W1n + (2 * k2 + 1) * 30 + 2 * lane;
                acc0 = fmaf(rk0, w0[0], acc0);
                acc1 = fmaf(rk0, w0[1], acc1);
                acc0 = fmaf(rk1, w1[0], acc0);
                acc1 = fmaf(rk1, w1[1], acc1);
            }
        }
        if (lane < 15) {
            bufn[(size_t)gh * 30 + 2 * lane] = acc0;
            bufn[(size_t)gh * 30 + 2 * lane + 1] = acc1;
        }
    } else {
        float acc = b1n[0];
        for (int k2 = 0; k2 < 15; ++k2) {
            float rk0 = __shfl(r0, k2, 16);
            float rk1 = __shfl(r1, k2, 16);
            acc = fmaf(rk0, W1n[2 * k2], acc);
            acc = fmaf(rk1, W1n[2 * k2 + 1], acc);
        }
        if (lane == 0) bufn[gh] = acc;
    }
}

// Final aggregation, compact msg1[e]: out[gh] += sum (same lane->j order)
__global__ __launch_bounds__(256) void agg_last(const bf16* __restrict__ msg1,
                                                const int* __restrict__ offsets,
                                                float* __restrict__ out) {
    int gh = (blockIdx.x * 256 + threadIdx.x) >> 5;
    int lane = threadIdx.x & 31;
    int s0 = offsets[gh], s1 = offsets[gh + 1];
    float v = 0.f;
    for (int j = s0 + lane; j < s1; j += 32) v += (float)msg1[j];
#pragma unroll
    for (int o = 16; o > 0; o >>= 1) v += __shfl_xor(v, o);
    if (lane == 0) out[gh] += v;
}

// ===========================================================================
extern "C" void kernel_launch(void* const* d_in, const int* in_sizes, int n_in,
                              void* d_out, int out_size, void* d_ws, size_t ws_size,
                              hipStream_t stream) {
    const float* features = (const float*)d_in[0];
    const int*   edges    = (const int*)d_in[1];
    const float* ew       = (const float*)d_in[2];

    const float* W1_d  = (const float*)d_in[3];
    const float* b1_d  = (const float*)d_in[4];
    const float* Wm1_d = (const float*)d_in[5];
    const float* bm1_d = (const float*)d_in[6];
    const float* Wm2_d = (const float*)d_in[7];
    const float* bm2_d = (const float*)d_in[8];
    const float* W2_d  = (const float*)d_in[9];
    const float* b2_d  = (const float*)d_in[10];

    const float* W1_h  = (const float*)d_in[11];
    const float* b1_h  = (const float*)d_in[12];
    const float* Wm1_h = (const float*)d_in[13];
    const float* bm1_h = (const float*)d_in[14];
    const float* Wm2_h = (const float*)d_in[15];
    const float* bm2_h = (const float*)d_in[16];
    const float* W2_h  = (const float*)d_in[17];
    const float* b2_h  = (const float*)d_in[18];

    const float* W1_o  = (const float*)d_in[19];
    const float* b1_o  = (const float*)d_in[20];
    const float* Wm1_o = (const float*)d_in[21];
    const float* bm1_o = (const float*)d_in[22];
    const float* Wm2_o = (const float*)d_in[23];
    const float* bm2_o = (const float*)d_in[24];
    const float* W2_o  = (const float*)d_in[25];
    const float* b2_o  = (const float*)d_in[26];

    const int* src = edges;
    const int* dst = edges + N_EDGES;
    float* out = (float*)d_out;

    // ---- workspace carve-up ----
    char* p = (char*)d_ws;
    auto alloc = [&](size_t bytes) { char* r = p; p += (bytes + 63) & ~(size_t)63; return r; };
    float* bufA    = (float*)alloc((size_t)N_NODES * 30 * 4);
    float* bufB    = (float*)alloc((size_t)N_NODES * 30 * 4);
    bf16*  msg     = (bf16*) alloc((size_t)N_EDGES * 32 * 2);
    bf16*  xbf     = (bf16*) alloc((size_t)N_NODES * 32 * 2);
    bf16*  xlo     = (bf16*) alloc((size_t)N_NODES * 32 * 2);
    int*   counts  = (int*)  alloc((size_t)N_NODES * 4);
    int*   offsets = (int*)  alloc((size_t)(N_NODES + 1) * 4);
    int*   cursor  = (int*)  alloc((size_t)N_NODES * 4);
    int4*  edata   = (int4*) alloc((size_t)N_EDGES * 16);
    float* Wm1T_d  = (float*)alloc((size_t)C_MSG * 4 * 4);
    bf16*  Wm1B_h  = (bf16*) alloc((size_t)26 * 512 * 2);
    bf16*  Wm1B_o  = (bf16*) alloc((size_t)26 * 512 * 2);
    bf16*  Wm2B_h  = (bf16*) alloc((size_t)14 * 512 * 2);
    bf16*  Wm2B_o  = (bf16*) alloc((size_t)14 * 512 * 2);
    bf16*  W2B_h   = (bf16*) alloc((size_t)2 * 512 * 2);
    bf16*  W2B_o   = (bf16*) alloc((size_t)1 * 512 * 2);
    bf16*  SelB    = (bf16*) alloc((size_t)8 * 512 * 2);

    // ---- setup ----
    hipMemsetAsync(counts, 0, (size_t)N_NODES * 4, stream);
    setup_a<<<3507, 256, 0, stream>>>(dst, counts,
        Wm1_h, bm1_h, Wm1_o, bm1_o, Wm2_h, bm2_h, Wm2_o, bm2_o,
        W2_h, b2_h, W2_o, b2_o, Wm1_d,
        Wm1B_h, Wm1B_o, Wm2B_h, Wm2B_o, W2B_h, W2B_o, SelB, Wm1T_d,
        features, W1_d, b1_d, bufA);
    scan_kernel<<<(N_NODES + 255) / 256, 256, 0, stream>>>(counts, offsets, cursor);
    scatter_kernel<<<N_EDGES / 256, 256, 0, stream>>>(src, dst, ew, cursor, edata);

    dim3 tb(256);
    dim3 eb_mfma(N_EDGES / 64);
    dim3 eb_valu(N_EDGES / 256);
    dim3 ab16(N_NODES * 16 / 256);
    dim3 ab32(N_NODES * 32 / 256);

    // ---- layer d ----
    edge_d_kernel<<<eb_valu, tb, 0, stream>>>(features, edata, ew,
        Wm1T_d, bm1_d, Wm2_d, bm2_d, W2_d, b2_d, msg);
    agg_fused<30><<<ab16, tb, 0, stream>>>(msg, offsets, bufA, W1_h, b1_h, bufB, xbf, xlo);

    // ---- h1 ----
    edge_mfma<30><<<eb_mfma, tb, 0, stream>>>(xbf, xlo, edata,
        Wm1B_h, SelB, Wm2B_h, W2B_h, msg);
    agg_fused<30><<<ab16, tb, 0, stream>>>(msg, offsets, bufB, W1_h, b1_h, bufA, xbf, xlo);

    // ---- h2 ----
    edge_mfma<30><<<eb_mfma, tb, 0, stream>>>(xbf, xlo, edata,
        Wm1B_h, SelB, Wm2B_h, W2B_h, msg);
    agg_fused<30><<<ab16, tb, 0, stream>>>(msg, offsets, bufA, W1_h, b1_h, bufB, xbf, xlo);

    // ---- h3 (next node term = output layer -> writes d_out) ----
    edge_mfma<30><<<eb_mfma, tb, 0, stream>>>(xbf, xlo, edata,
        Wm1B_h, SelB, Wm2B_h, W2B_h, msg);
    agg_fused<1><<<ab16, tb, 0, stream>>>(msg, offsets, bufB, W1_o, b1_o, out, xbf, xlo);

    // ---- output layer (compact msg1) ----
    edge_mfma<1><<<eb_mfma, tb, 0, stream>>>(xbf, xlo, edata,
        Wm1B_o, SelB, Wm2B_o, W2B_o, msg);
    agg_last<<<ab32, tb, 0, stream>>>(msg, offsets, out);
}